// Round 2
// baseline (3444.806 us; speedup 1.0000x reference)
//
#include <hip/hip_runtime.h>
#include <hip/hip_bf16.h>

#define BATCHN 512
#define SEQL 28
#define DIMM 512
#define DINNER 1024
#define DSTATE 16
#define DTRANK 32
#define XDBW 64                 // DT_RANK + 2*D_STATE
#define EPSV 1e-6f

typedef __hip_bfloat16 bf16;

__device__ __forceinline__ float ldf(const float* p, size_t i) { return p[i]; }
__device__ __forceinline__ float ldf(const bf16* p, size_t i) { return __bfloat162float(p[i]); }
__device__ __forceinline__ void stf(float* p, size_t i, float v) { p[i] = v; }
__device__ __forceinline__ void stf(bf16* p, size_t i, float v) { p[i] = __float2bfloat16(v); }

// ---------------- row projection: h[r,d] = W[d,:28] . x[r,:28] + b[d] ----------------
__global__ void row_proj_kernel(const float* __restrict__ x,
                                const float* __restrict__ w,
                                const float* __restrict__ b,
                                float* __restrict__ h) {
    int row = blockIdx.x;
    int d = blockIdx.y * blockDim.x + threadIdx.x;
    __shared__ float xin[28];
    if (threadIdx.x < 28) xin[threadIdx.x] = x[row * 28 + threadIdx.x];
    __syncthreads();
    float acc = b[d];
#pragma unroll
    for (int k = 0; k < 28; ++k) acc = fmaf(w[d * 28 + k], xin[k], acc);
    h[(size_t)row * DIMM + d] = acc;
}

// ---------------- per-row inverse RMS (norm itself fused into GEMM A-load) ----------------
__global__ void rms_calc_kernel(const float* __restrict__ h, float* __restrict__ rms) {
    int row = blockIdx.x * blockDim.y + threadIdx.y;
    int lane = threadIdx.x;
    const float4* p = (const float4*)(h + (size_t)row * DIMM);
    float4 v0 = p[lane * 2], v1 = p[lane * 2 + 1];
    float ss = v0.x * v0.x + v0.y * v0.y + v0.z * v0.z + v0.w * v0.w +
               v1.x * v1.x + v1.y * v1.y + v1.z * v1.z + v1.w * v1.w;
#pragma unroll
    for (int off = 32; off > 0; off >>= 1) ss += __shfl_down(ss, off);
    if (lane == 0) rms[row] = rsqrtf(ss * (1.f / DIMM) + EPSV);
}

// ---------------- generic tiled GEMM: C = op(A)(MxK) * W(NxK)^T [+bias][act][+=C] ----------------
// TA: A dtype (float/bf16). TC: C dtype. ACT: 0=none 1=softplus.
// FRMS: A element scaled by rms[row]*nw[k]  (fused RMSNorm)
template <typename TA, typename TC, int ACT, bool ADDC, bool HASBIAS, bool FRMS>
__global__ __launch_bounds__(256) void gemm_tn(const TA* __restrict__ A, int lda,
                                               const float* __restrict__ W,
                                               const float* __restrict__ bias,
                                               TC* C, int ldc,
                                               int M, int N, int K,
                                               const float* __restrict__ rms,
                                               const float* __restrict__ nw) {
    const int BM = 64, BN = 64, BK = 16;
    __shared__ float As[BK][BM + 4];
    __shared__ float Bs[BK][BN + 4];
    int bm = blockIdx.x * BM;
    int bn = blockIdx.y * BN;
    int t = threadIdx.x;
    int tx = t & 15, ty = t >> 4;
    float acc[4][4] = {};
    for (int k0 = 0; k0 < K; k0 += BK) {
#pragma unroll
        for (int i = 0; i < 4; ++i) {
            int idx = t + i * 256;
            int m = idx >> 4, k = idx & 15;
            float a = ldf(A, (size_t)(bm + m) * lda + k0 + k);
            if (FRMS) a *= rms[bm + m] * nw[k0 + k];
            As[k][m] = a;
            Bs[k][m] = W[(size_t)(bn + m) * K + k0 + k];
        }
        __syncthreads();
#pragma unroll
        for (int k = 0; k < BK; ++k) {
            float a[4], bb[4];
#pragma unroll
            for (int j = 0; j < 4; ++j) a[j] = As[k][ty * 4 + j];
#pragma unroll
            for (int i = 0; i < 4; ++i) bb[i] = Bs[k][tx * 4 + i];
#pragma unroll
            for (int j = 0; j < 4; ++j)
#pragma unroll
                for (int i = 0; i < 4; ++i)
                    acc[j][i] = fmaf(a[j], bb[i], acc[j][i]);
        }
        __syncthreads();
    }
#pragma unroll
    for (int j = 0; j < 4; ++j) {
        int m = bm + ty * 4 + j;
#pragma unroll
        for (int i = 0; i < 4; ++i) {
            int n = bn + tx * 4 + i;
            float v = acc[j][i];
            if (HASBIAS) v += bias[n];
            if (ACT == 1) v = (v > 20.f) ? v : log1pf(__expf(v));
            size_t off = (size_t)m * ldc + n;
            if (ADDC) v += ldf(C, off);
            stf(C, off, v);
        }
    }
}

// ---------------- depthwise causal conv (k=4) + SiLU; thread per (b,d) ----------------
__global__ void conv_silu_kernel(const bf16* __restrict__ xp,
                                 const float* __restrict__ cw,
                                 const float* __restrict__ cb,
                                 bf16* __restrict__ xc) {
    int gid = blockIdx.x * blockDim.x + threadIdx.x;
    int b = gid >> 10, d = gid & (DINNER - 1);
    float w0 = cw[d * 4 + 0], w1 = cw[d * 4 + 1], w2 = cw[d * 4 + 2], w3 = cw[d * 4 + 3];
    float bias = cb[d];
    const bf16* src = xp + (size_t)b * SEQL * DINNER + d;
    bf16* dst = xc + (size_t)b * SEQL * DINNER + d;
    float x0 = 0.f, x1 = 0.f, x2 = 0.f;
#pragma unroll
    for (int t = 0; t < SEQL; ++t) {
        float x3 = __bfloat162float(src[(size_t)t * DINNER]);
        float v = fmaf(w0, x0, fmaf(w1, x1, fmaf(w2, x2, fmaf(w3, x3, bias))));
        float s = 1.f / (1.f + __expf(-v));
        dst[(size_t)t * DINNER] = __float2bfloat16(v * s);
        x0 = x1; x1 = x2; x2 = x3;
    }
}

// ---------------- selective scan + gating; thread per (b,d); y overwrites dt ----------------
__global__ void scan_kernel(const bf16* __restrict__ xc,
                            bf16* dty,  // in: dt, out: gated y
                            const float* __restrict__ xdb,
                            const bf16* __restrict__ z,
                            const float* __restrict__ A_log,
                            const float* __restrict__ Dp) {
    int gid = blockIdx.x * blockDim.x + threadIdx.x;
    int b = gid >> 10, d = gid & (DINNER - 1);
    __shared__ float BC[SEQL][32];
    for (int idx = threadIdx.x; idx < SEQL * 32; idx += blockDim.x) {
        int t = idx >> 5, j = idx & 31;
        BC[t][j] = xdb[((size_t)b * SEQL + t) * XDBW + 32 + j];
    }
    __syncthreads();
    float Ac[DSTATE];
#pragma unroll
    for (int s = 0; s < DSTATE; ++s) Ac[s] = -__expf(A_log[d * DSTATE + s]);
    float Dd = Dp[d];
    float st[DSTATE];
#pragma unroll
    for (int s = 0; s < DSTATE; ++s) st[s] = 0.f;
    for (int t = 0; t < SEQL; ++t) {
        size_t off = ((size_t)b * SEQL + t) * DINNER + d;
        float dtt = __bfloat162float(dty[off]);
        float xt = __bfloat162float(xc[off]);
        float zt = __bfloat162float(z[off]);
        float dtx = dtt * xt;
        float yt = 0.f;
#pragma unroll
        for (int s = 0; s < DSTATE; ++s) {
            float dA = __expf(dtt * Ac[s]);
            st[s] = fmaf(st[s], dA, dtx * BC[t][s]);
            yt = fmaf(st[s], BC[t][16 + s], yt);
        }
        float sz = zt / (1.f + __expf(-zt));
        dty[off] = __float2bfloat16((yt + Dd * xt) * sz);
    }
}

// ---------------- final RMSNorm(last token) + classifier ----------------
__global__ void head_kernel(const float* __restrict__ h,
                            const float* __restrict__ fw,
                            const float* __restrict__ clsw,
                            const float* __restrict__ clsb,
                            float* __restrict__ out) {
    int b = blockIdx.x;
    int lane = threadIdx.x;
    const float* row = h + ((size_t)b * SEQL + (SEQL - 1)) * DIMM;
    const float4* p = (const float4*)row;
    float4 v0 = p[lane * 2], v1 = p[lane * 2 + 1];
    float ss = v0.x * v0.x + v0.y * v0.y + v0.z * v0.z + v0.w * v0.w +
               v1.x * v1.x + v1.y * v1.y + v1.z * v1.z + v1.w * v1.w;
#pragma unroll
    for (int off = 32; off > 0; off >>= 1) ss += __shfl_down(ss, off);
    ss = __shfl(ss, 0);
    float inv = rsqrtf(ss * (1.f / DIMM) + EPSV);
    const float4* wp = (const float4*)fw;
    float4 w0 = wp[lane * 2], w1 = wp[lane * 2 + 1];
    float nv[8];
    nv[0] = v0.x * inv * w0.x; nv[1] = v0.y * inv * w0.y;
    nv[2] = v0.z * inv * w0.z; nv[3] = v0.w * inv * w0.w;
    nv[4] = v1.x * inv * w1.x; nv[5] = v1.y * inv * w1.y;
    nv[6] = v1.z * inv * w1.z; nv[7] = v1.w * inv * w1.w;
    for (int c = 0; c < 10; ++c) {
        const float* cr = clsw + (size_t)c * DIMM + lane * 8;
        float pacc = 0.f;
#pragma unroll
        for (int j = 0; j < 8; ++j) pacc = fmaf(nv[j], cr[j], pacc);
#pragma unroll
        for (int off = 32; off > 0; off >>= 1) pacc += __shfl_down(pacc, off);
        if (lane == 0) out[b * 10 + c] = pacc + clsb[c];
    }
}

extern "C" void kernel_launch(void* const* d_in, const int* in_sizes, int n_in,
                              void* d_out, int out_size, void* d_ws, size_t ws_size,
                              hipStream_t stream) {
    const float* x     = (const float*)d_in[0];
    const float* rpw   = (const float*)d_in[1];
    const float* rpb   = (const float*)d_in[2];
    const float* normw = (const float*)d_in[3];
    const float* inpw  = (const float*)d_in[4];
    const float* inpb  = (const float*)d_in[5];
    const float* convw = (const float*)d_in[6];
    const float* convb = (const float*)d_in[7];
    const float* xpw   = (const float*)d_in[8];
    const float* dtpw  = (const float*)d_in[9];
    const float* dtpb  = (const float*)d_in[10];
    const float* alog  = (const float*)d_in[11];
    const float* Dp    = (const float*)d_in[12];
    const float* outpw = (const float*)d_in[13];
    const float* outpb = (const float*)d_in[14];
    const float* fnw   = (const float*)d_in[15];
    const float* clsw  = (const float*)d_in[16];
    const float* clsb  = (const float*)d_in[17];
    float* out = (float*)d_out;

    // per-row workspace bytes: h(f32,512) + rms(f32) + 3x bf16 1024-wide + xdb(f32,64)
    // dt/y reuses the xp slot (dead after conv).
    const size_t per_row = 512 * 4 + 4 + 3 * (1024 * 2) + 64 * 4;  // 8452 B
    const int cand[6] = {512, 256, 128, 64, 32, 16};
    int Bc = 16;
    for (int i = 0; i < 6; ++i) {
        size_t R = (size_t)cand[i] * SEQL;
        if (R * per_row + 4096 <= ws_size) { Bc = cand[i]; break; }
    }
    const int chunks = BATCHN / Bc;
    const int R = Bc * SEQL;  // rows per chunk, multiple of 64 (Bc multiple of 16)

    char* base = (char*)d_ws;
    float* h   = (float*)base; base += (size_t)R * DIMM * 4;
    float* rms = (float*)base; base += (size_t)R * 4;
    bf16* xp   = (bf16*)base;  base += (size_t)R * DINNER * 2;
    bf16* zb   = (bf16*)base;  base += (size_t)R * DINNER * 2;
    bf16* xcb  = (bf16*)base;  base += (size_t)R * DINNER * 2;
    float* xdb = (float*)base; base += (size_t)R * XDBW * 4;
    bf16* dty  = xp;  // reuse

    for (int c = 0; c < chunks; ++c) {
        const int b0 = c * Bc;
        row_proj_kernel<<<dim3(R, DIMM / 256), 256, 0, stream>>>(
            x + (size_t)b0 * 784, rpw, rpb, h);

        for (int l = 0; l < 4; ++l) {
            rms_calc_kernel<<<R / 4, dim3(64, 4), 0, stream>>>(h, rms);

            // xpart = rmsnorm(h) @ Wx^T + bx   (R x 1024, K=512)
            gemm_tn<float, bf16, 0, false, true, true><<<dim3(R / 64, DINNER / 64), 256, 0, stream>>>(
                h, DIMM, inpw + (size_t)l * 2 * DINNER * DIMM, inpb + (size_t)l * 2 * DINNER,
                xp, DINNER, R, DINNER, DIMM, rms, normw + (size_t)l * DIMM);
            // z = rmsnorm(h) @ Wz^T + bz
            gemm_tn<float, bf16, 0, false, true, true><<<dim3(R / 64, DINNER / 64), 256, 0, stream>>>(
                h, DIMM, inpw + (size_t)l * 2 * DINNER * DIMM + (size_t)DINNER * DIMM,
                inpb + (size_t)l * 2 * DINNER + DINNER,
                zb, DINNER, R, DINNER, DIMM, rms, normw + (size_t)l * DIMM);

            conv_silu_kernel<<<(Bc * DINNER) / 256, 256, 0, stream>>>(
                xp, convw + (size_t)l * DINNER * 4, convb + (size_t)l * DINNER, xcb);

            // xdb = xc @ x_proj_w^T   (R x 64, K=1024)
            gemm_tn<bf16, float, 0, false, false, false><<<dim3(R / 64, XDBW / 64), 256, 0, stream>>>(
                xcb, DINNER, xpw + (size_t)l * XDBW * DINNER, nullptr,
                xdb, XDBW, R, XDBW, DINNER, nullptr, nullptr);

            // dt = softplus(xdb[:, :32] @ dt_proj_w^T + b)   (R x 1024, K=32) -> into xp slot
            gemm_tn<float, bf16, 1, false, true, false><<<dim3(R / 64, DINNER / 64), 256, 0, stream>>>(
                xdb, XDBW, dtpw + (size_t)l * DINNER * DTRANK, dtpb + (size_t)l * DINNER,
                dty, DINNER, R, DINNER, DTRANK, nullptr, nullptr);

            scan_kernel<<<(Bc * DINNER) / 256, 256, 0, stream>>>(
                xcb, dty, xdb, zb, alog + (size_t)l * DINNER * DSTATE, Dp + (size_t)l * DINNER);

            // h += y @ out_proj_w^T + b   (R x 512, K=1024)
            gemm_tn<bf16, float, 0, true, true, false><<<dim3(R / 64, DIMM / 64), 256, 0, stream>>>(
                dty, DINNER, outpw + (size_t)l * DIMM * DINNER, outpb + (size_t)l * DIMM,
                h, DIMM, R, DIMM, DINNER, nullptr, nullptr);
        }
        head_kernel<<<Bc, 64, 0, stream>>>(h, fnw, clsw, clsb, out + (size_t)b0 * 10);
    }
}

// Round 3
// 1322.427 us; speedup vs baseline: 2.6049x; 2.6049x over previous
//
#include <hip/hip_runtime.h>
#include <hip/hip_bf16.h>

#define BATCHN 512
#define SEQL 28
#define DIMM 512
#define DINNER 1024
#define DSTATE 16
#define DTRANK 32
#define XDBW 64                 // DT_RANK + 2*D_STATE
#define EPSV 1e-6f
#define LDK 40                  // padded LDS row stride (bf16) for BK=32: 80B -> 2-way conflict only

typedef __hip_bfloat16 bf16;
using f32x4 = __attribute__((ext_vector_type(4))) float;
using bf16x8 = __attribute__((ext_vector_type(8))) short;

__device__ __forceinline__ float ldf(const float* p, size_t i) { return p[i]; }
__device__ __forceinline__ float ldf(const bf16* p, size_t i) { return __bfloat162float(p[i]); }
__device__ __forceinline__ void stf(float* p, size_t i, float v) { p[i] = v; }
__device__ __forceinline__ void stf(bf16* p, size_t i, float v) { p[i] = __float2bfloat16(v); }

// ---------------- row projection: h[r,d] = W[d,:28] . x[r,:28] + b[d] ----------------
__global__ void row_proj_kernel(const float* __restrict__ x,
                                const float* __restrict__ w,
                                const float* __restrict__ b,
                                float* __restrict__ h) {
    int row = blockIdx.x;
    int d = blockIdx.y * blockDim.x + threadIdx.x;
    __shared__ float xin[28];
    if (threadIdx.x < 28) xin[threadIdx.x] = x[row * 28 + threadIdx.x];
    __syncthreads();
    float acc = b[d];
#pragma unroll
    for (int k = 0; k < 28; ++k) acc = fmaf(w[d * 28 + k], xin[k], acc);
    h[(size_t)row * DIMM + d] = acc;
}

// ---------------- per-row inverse RMS (norm itself fused into GEMM A-load) ----------------
__global__ void rms_calc_kernel(const float* __restrict__ h, float* __restrict__ rms) {
    int row = blockIdx.x * blockDim.y + threadIdx.y;
    int lane = threadIdx.x;
    const float4* p = (const float4*)(h + (size_t)row * DIMM);
    float4 v0 = p[lane * 2], v1 = p[lane * 2 + 1];
    float ss = v0.x * v0.x + v0.y * v0.y + v0.z * v0.z + v0.w * v0.w +
               v1.x * v1.x + v1.y * v1.y + v1.z * v1.z + v1.w * v1.w;
#pragma unroll
    for (int off = 32; off > 0; off >>= 1) ss += __shfl_down(ss, off);
    if (lane == 0) rms[row] = rsqrtf(ss * (1.f / DIMM) + EPSV);
}

// ---------------- MFMA GEMM: C = op(A)(M x K) * W(N x K)^T [+bias][act][+=C] ----------------
// TA in {float, bf16}; W always f32 (converted to bf16 during LDS staging).
// BN in {128, 64}. ACT: 0=none 1=softplus. FRMS: A[m][k] *= rms[m]*nw[k].
template <typename TA, typename TC, int BN, int ACT, bool ADDC, bool HASBIAS, bool FRMS>
__global__ __launch_bounds__(256) void gemm_mfma(const TA* __restrict__ A, int lda,
                                                 const float* __restrict__ W,
                                                 const float* __restrict__ bias,
                                                 TC* __restrict__ C, int ldc,
                                                 int K,
                                                 const float* __restrict__ rms,
                                                 const float* __restrict__ nw) {
    constexpr int BM = 128;
    constexpr int BK = 32;
    constexpr int MI = (BN == 128) ? 4 : 2;   // 16-row fragments per wave
    constexpr int NI = 4;                     // 16-col fragments per wave
    __shared__ bf16 As[BM * LDK];
    __shared__ bf16 Bs[BN * LDK];

    const int t = threadIdx.x;
    const int w = t >> 6, l = t & 63;
    const int bm = blockIdx.x * BM;
    const int bn = blockIdx.y * BN;
    const int wm = (BN == 128) ? (w >> 1) * 64 : w * 32;
    const int wn = (BN == 128) ? (w & 1) * 64 : 0;

    f32x4 acc[MI][NI] = {};

    constexpr int EA = BM * BK / 256;  // elems per thread for A staging (16)
    constexpr int EB = BN * BK / 256;  // 16 or 8

    for (int k0 = 0; k0 < K; k0 += BK) {
        __syncthreads();
        // ---- stage A tile (BM x 32) as bf16 ----
#pragma unroll
        for (int c = 0; c < EA / 8; ++c) {
            int flat = t * EA + c * 8;
            int row = flat >> 5;
            int kk = flat & 31;
            bf16 tmp[8];
            if constexpr (sizeof(TA) == 4) {
                const float4* src = (const float4*)(A + (size_t)(bm + row) * lda + k0 + kk);
                float4 v0 = src[0], v1 = src[1];
                float vals[8] = {v0.x, v0.y, v0.z, v0.w, v1.x, v1.y, v1.z, v1.w};
                float s = FRMS ? rms[bm + row] : 1.f;
#pragma unroll
                for (int j = 0; j < 8; ++j) {
                    float v = vals[j];
                    if (FRMS) v *= s * nw[k0 + kk + j];
                    tmp[j] = __float2bfloat16(v);
                }
            } else {
                *(uint4*)tmp = *(const uint4*)(A + (size_t)(bm + row) * lda + k0 + kk);
            }
            *(uint4*)(&As[row * LDK + kk]) = *(uint4*)tmp;
        }
        // ---- stage B tile (BN x 32) from f32 W ----
#pragma unroll
        for (int c = 0; c < EB / 8; ++c) {
            int flat = t * EB + c * 8;
            int row = flat >> 5;
            int kk = flat & 31;
            const float4* src = (const float4*)(W + (size_t)(bn + row) * K + k0 + kk);
            float4 v0 = src[0], v1 = src[1];
            float vals[8] = {v0.x, v0.y, v0.z, v0.w, v1.x, v1.y, v1.z, v1.w};
            bf16 tmp[8];
#pragma unroll
            for (int j = 0; j < 8; ++j) tmp[j] = __float2bfloat16(vals[j]);
            *(uint4*)(&Bs[row * LDK + kk]) = *(uint4*)tmp;
        }
        __syncthreads();
        // ---- MFMA over the K=32 step ----
        bf16x8 af[MI], bfr[NI];
#pragma unroll
        for (int mi = 0; mi < MI; ++mi)
            af[mi] = *(const bf16x8*)(&As[(wm + mi * 16 + (l & 15)) * LDK + (l >> 4) * 8]);
#pragma unroll
        for (int ni = 0; ni < NI; ++ni)
            bfr[ni] = *(const bf16x8*)(&Bs[(wn + ni * 16 + (l & 15)) * LDK + (l >> 4) * 8]);
#pragma unroll
        for (int mi = 0; mi < MI; ++mi)
#pragma unroll
            for (int ni = 0; ni < NI; ++ni)
                acc[mi][ni] = __builtin_amdgcn_mfma_f32_16x16x32_bf16(af[mi], bfr[ni], acc[mi][ni], 0, 0, 0);
    }

    // ---- epilogue: C/D layout col=lane&15, row=(lane>>4)*4+r ----
#pragma unroll
    for (int mi = 0; mi < MI; ++mi) {
#pragma unroll
        for (int ni = 0; ni < NI; ++ni) {
            int col = bn + wn + ni * 16 + (l & 15);
            int rowb = bm + wm + mi * 16 + ((l >> 4) << 2);
            float bv = HASBIAS ? bias[col] : 0.f;
#pragma unroll
            for (int r = 0; r < 4; ++r) {
                float v = acc[mi][ni][r] + bv;
                if (ACT == 1) v = (v > 20.f) ? v : log1pf(__expf(v));
                size_t off = (size_t)(rowb + r) * ldc + col;
                if (ADDC) v += ldf(C, off);
                stf(C, off, v);
            }
        }
    }
}

// ---------------- depthwise causal conv (k=4) + SiLU; thread per (b,d) ----------------
// reads x-part of interleaved xz (stride 2048), writes contiguous xc (stride 1024)
__global__ void conv_silu_kernel(const bf16* __restrict__ xz,
                                 const float* __restrict__ cw,
                                 const float* __restrict__ cb,
                                 bf16* __restrict__ xc) {
    int gid = blockIdx.x * blockDim.x + threadIdx.x;
    int b = gid >> 10, d = gid & (DINNER - 1);
    float w0 = cw[d * 4 + 0], w1 = cw[d * 4 + 1], w2 = cw[d * 4 + 2], w3 = cw[d * 4 + 3];
    float bias = cb[d];
    const bf16* src = xz + (size_t)b * SEQL * (2 * DINNER) + d;
    bf16* dst = xc + (size_t)b * SEQL * DINNER + d;
    float x0 = 0.f, x1 = 0.f, x2 = 0.f;
#pragma unroll
    for (int t = 0; t < SEQL; ++t) {
        float x3 = __bfloat162float(src[(size_t)t * (2 * DINNER)]);
        float v = fmaf(w0, x0, fmaf(w1, x1, fmaf(w2, x2, fmaf(w3, x3, bias))));
        float s = 1.f / (1.f + __expf(-v));
        dst[(size_t)t * DINNER] = __float2bfloat16(v * s);
        x0 = x1; x1 = x2; x2 = x3;
    }
}

// ---------------- selective scan + gating; thread per (b,d); y overwrites dt (stride 2048) ----------------
__global__ void scan_kernel(const bf16* __restrict__ xc,
                            bf16* dty,  // in: dt, out: gated y (x-half of xz, stride 2048)
                            const float* __restrict__ xdb,
                            const bf16* __restrict__ xz,   // z at +1024, stride 2048
                            const float* __restrict__ A_log,
                            const float* __restrict__ Dp) {
    int gid = blockIdx.x * blockDim.x + threadIdx.x;
    int b = gid >> 10, d = gid & (DINNER - 1);
    __shared__ float BC[SEQL][32];
    for (int idx = threadIdx.x; idx < SEQL * 32; idx += blockDim.x) {
        int t = idx >> 5, j = idx & 31;
        BC[t][j] = xdb[((size_t)b * SEQL + t) * XDBW + 32 + j];
    }
    __syncthreads();
    float Ac[DSTATE];
#pragma unroll
    for (int s = 0; s < DSTATE; ++s) Ac[s] = -__expf(A_log[d * DSTATE + s]);
    float Dd = Dp[d];
    float st[DSTATE];
#pragma unroll
    for (int s = 0; s < DSTATE; ++s) st[s] = 0.f;
    for (int t = 0; t < SEQL; ++t) {
        size_t roff = ((size_t)b * SEQL + t) * (2 * DINNER);
        float dtt = __bfloat162float(dty[roff + d]);
        float xt = __bfloat162float(xc[((size_t)b * SEQL + t) * DINNER + d]);
        float zt = __bfloat162float(xz[roff + DINNER + d]);
        float dtx = dtt * xt;
        float yt = 0.f;
#pragma unroll
        for (int s = 0; s < DSTATE; ++s) {
            float dA = __expf(dtt * Ac[s]);
            st[s] = fmaf(st[s], dA, dtx * BC[t][s]);
            yt = fmaf(st[s], BC[t][16 + s], yt);
        }
        float sz = zt / (1.f + __expf(-zt));
        dty[roff + d] = __float2bfloat16((yt + Dd * xt) * sz);
    }
}

// ---------------- final RMSNorm(last token) + classifier ----------------
__global__ void head_kernel(const float* __restrict__ h,
                            const float* __restrict__ fw,
                            const float* __restrict__ clsw,
                            const float* __restrict__ clsb,
                            float* __restrict__ out) {
    int b = blockIdx.x;
    int lane = threadIdx.x;
    const float* row = h + ((size_t)b * SEQL + (SEQL - 1)) * DIMM;
    const float4* p = (const float4*)row;
    float4 v0 = p[lane * 2], v1 = p[lane * 2 + 1];
    float ss = v0.x * v0.x + v0.y * v0.y + v0.z * v0.z + v0.w * v0.w +
               v1.x * v1.x + v1.y * v1.y + v1.z * v1.z + v1.w * v1.w;
#pragma unroll
    for (int off = 32; off > 0; off >>= 1) ss += __shfl_down(ss, off);
    ss = __shfl(ss, 0);
    float inv = rsqrtf(ss * (1.f / DIMM) + EPSV);
    const float4* wp = (const float4*)fw;
    float4 w0 = wp[lane * 2], w1 = wp[lane * 2 + 1];
    float nv[8];
    nv[0] = v0.x * inv * w0.x; nv[1] = v0.y * inv * w0.y;
    nv[2] = v0.z * inv * w0.z; nv[3] = v0.w * inv * w0.w;
    nv[4] = v1.x * inv * w1.x; nv[5] = v1.y * inv * w1.y;
    nv[6] = v1.z * inv * w1.z; nv[7] = v1.w * inv * w1.w;
    for (int c = 0; c < 10; ++c) {
        const float* cr = clsw + (size_t)c * DIMM + lane * 8;
        float pacc = 0.f;
#pragma unroll
        for (int j = 0; j < 8; ++j) pacc = fmaf(nv[j], cr[j], pacc);
#pragma unroll
        for (int off = 32; off > 0; off >>= 1) pacc += __shfl_down(pacc, off);
        if (lane == 0) out[b * 10 + c] = pacc + clsb[c];
    }
}

extern "C" void kernel_launch(void* const* d_in, const int* in_sizes, int n_in,
                              void* d_out, int out_size, void* d_ws, size_t ws_size,
                              hipStream_t stream) {
    const float* x     = (const float*)d_in[0];
    const float* rpw   = (const float*)d_in[1];
    const float* rpb   = (const float*)d_in[2];
    const float* normw = (const float*)d_in[3];
    const float* inpw  = (const float*)d_in[4];
    const float* inpb  = (const float*)d_in[5];
    const float* convw = (const float*)d_in[6];
    const float* convb = (const float*)d_in[7];
    const float* xpw   = (const float*)d_in[8];
    const float* dtpw  = (const float*)d_in[9];
    const float* dtpb  = (const float*)d_in[10];
    const float* alog  = (const float*)d_in[11];
    const float* Dp    = (const float*)d_in[12];
    const float* outpw = (const float*)d_in[13];
    const float* outpb = (const float*)d_in[14];
    const float* fnw   = (const float*)d_in[15];
    const float* clsw  = (const float*)d_in[16];
    const float* clsb  = (const float*)d_in[17];
    float* out = (float*)d_out;

    // per-row bytes: h(f32,512) + rms(f32) + xz(bf16,2048) + xc(bf16,1024) + xdb(f32,64)
    const size_t per_row = 512 * 4 + 4 + 2048 * 2 + 1024 * 2 + 64 * 4;  // 8452 B
    const int cand[5] = {512, 256, 128, 64, 32};  // Bc*28 must be multiple of 128 -> Bc%32==0
    int Bc = 32;
    for (int i = 0; i < 5; ++i) {
        size_t R = (size_t)cand[i] * SEQL;
        if (R * per_row + 4096 <= ws_size) { Bc = cand[i]; break; }
    }
    const int chunks = BATCHN / Bc;
    const int R = Bc * SEQL;

    char* base = (char*)d_ws;
    float* h   = (float*)base; base += (size_t)R * DIMM * 4;
    float* rms = (float*)base; base += (size_t)R * 4;
    bf16* xz   = (bf16*)base;  base += (size_t)R * 2 * DINNER * 2;
    bf16* xcb  = (bf16*)base;  base += (size_t)R * DINNER * 2;
    float* xdb = (float*)base; base += (size_t)R * XDBW * 4;
    bf16* dty  = xz;  // x-half of xz is dead after conv; reuse for dt/y (stride 2048)

    for (int c = 0; c < chunks; ++c) {
        const int b0 = c * Bc;
        row_proj_kernel<<<dim3(R, DIMM / 256), 256, 0, stream>>>(
            x + (size_t)b0 * 784, rpw, rpb, h);

        for (int l = 0; l < 4; ++l) {
            rms_calc_kernel<<<R / 4, dim3(64, 4), 0, stream>>>(h, rms);

            // xz = rmsnorm(h) @ in_proj_w^T + b    (R x 2048, K=512)
            gemm_mfma<float, bf16, 128, 0, false, true, true>
                <<<dim3(R / 128, (2 * DINNER) / 128), 256, 0, stream>>>(
                h, DIMM, inpw + (size_t)l * 2 * DINNER * DIMM, inpb + (size_t)l * 2 * DINNER,
                xz, 2 * DINNER, DIMM, rms, normw + (size_t)l * DIMM);

            conv_silu_kernel<<<(Bc * DINNER) / 256, 256, 0, stream>>>(
                xz, convw + (size_t)l * DINNER * 4, convb + (size_t)l * DINNER, xcb);

            // xdb = xc @ x_proj_w^T    (R x 64, K=1024)
            gemm_mfma<bf16, float, 64, 0, false, false, false>
                <<<dim3(R / 128, 1), 256, 0, stream>>>(
                xcb, DINNER, xpw + (size_t)l * XDBW * DINNER, nullptr,
                xdb, XDBW, DINNER, nullptr, nullptr);

            // dt = softplus(xdb[:, :32] @ dt_proj_w^T + b)  (R x 1024, K=32) -> x-half of xz
            gemm_mfma<float, bf16, 128, 1, false, true, false>
                <<<dim3(R / 128, DINNER / 128), 256, 0, stream>>>(
                xdb, XDBW, dtpw + (size_t)l * DINNER * DTRANK, dtpb + (size_t)l * DINNER,
                dty, 2 * DINNER, DTRANK, nullptr, nullptr);

            scan_kernel<<<(Bc * DINNER) / 256, 256, 0, stream>>>(
                xcb, dty, xdb, xz, alog + (size_t)l * DINNER * DSTATE, Dp + (size_t)l * DINNER);

            // h += y @ out_proj_w^T + b   (R x 512, K=1024)
            gemm_mfma<bf16, float, 128, 0, true, true, false>
                <<<dim3(R / 128, DIMM / 128), 256, 0, stream>>>(
                dty, 2 * DINNER, outpw + (size_t)l * DIMM * DINNER, outpb + (size_t)l * DIMM,
                h, DIMM, DINNER, nullptr, nullptr);
        }
        head_kernel<<<Bc, 64, 0, stream>>>(h, fnw, clsw, clsb, out + (size_t)b0 * 10);
    }
}

// Round 4
// 1168.217 us; speedup vs baseline: 2.9488x; 1.1320x over previous
//
#include <hip/hip_runtime.h>
#include <hip/hip_bf16.h>

#define BATCHN 512
#define SEQL 28
#define DIMM 512
#define DINNER 1024
#define DSTATE 16
#define DTRANK 32
#define XDBW 64                 // DT_RANK + 2*D_STATE
#define EPSV 1e-6f
#define LDK 40                  // padded LDS row stride (bf16) for BK=32

typedef __hip_bfloat16 bf16;
using f32x4 = __attribute__((ext_vector_type(4))) float;
using bf16x8 = __attribute__((ext_vector_type(8))) short;

__device__ __forceinline__ float ldf(const float* p, size_t i) { return p[i]; }
__device__ __forceinline__ float ldf(const bf16* p, size_t i) { return __bfloat162float(p[i]); }
__device__ __forceinline__ void stf(float* p, size_t i, float v) { p[i] = v; }
__device__ __forceinline__ void stf(bf16* p, size_t i, float v) { p[i] = __float2bfloat16(v); }

// ---------------- row projection: h[r,d] = W[d,:28] . x[r,:28] + b[d] ----------------
__global__ void row_proj_kernel(const float* __restrict__ x,
                                const float* __restrict__ w,
                                const float* __restrict__ b,
                                float* __restrict__ h) {
    int row = blockIdx.x;
    int d = blockIdx.y * blockDim.x + threadIdx.x;
    __shared__ float xin[28];
    if (threadIdx.x < 28) xin[threadIdx.x] = x[row * 28 + threadIdx.x];
    __syncthreads();
    float acc = b[d];
#pragma unroll
    for (int k = 0; k < 28; ++k) acc = fmaf(w[d * 28 + k], xin[k], acc);
    h[(size_t)row * DIMM + d] = acc;
}

// ---------------- per-row inverse RMS (norm itself fused into GEMM A-load) ----------------
__global__ void rms_calc_kernel(const float* __restrict__ h, float* __restrict__ rms) {
    int row = blockIdx.x * blockDim.y + threadIdx.y;
    int lane = threadIdx.x;
    const float4* p = (const float4*)(h + (size_t)row * DIMM);
    float4 v0 = p[lane * 2], v1 = p[lane * 2 + 1];
    float ss = v0.x * v0.x + v0.y * v0.y + v0.z * v0.z + v0.w * v0.w +
               v1.x * v1.x + v1.y * v1.y + v1.z * v1.z + v1.w * v1.w;
#pragma unroll
    for (int off = 32; off > 0; off >>= 1) ss += __shfl_down(ss, off);
    if (lane == 0) rms[row] = rsqrtf(ss * (1.f / DIMM) + EPSV);
}

// ---------------- MFMA GEMM: C = op(A)(M x K) * W(N x K)^T [+bias][act][+=C] ----------------
// TA in {float, bf16}; W always f32 (converted to bf16 during LDS staging).
// (BM,BN) in {(128,128), (64,64)}. FRMS: A[m][k] *= rms[m]*nw[k].
// SPLITK: grid.z halves of K written to C + z*c_split.
template <typename TA, typename TC, int BM, int BN, int ACT, bool ADDC, bool HASBIAS, bool FRMS, int SPLITK>
__global__ __launch_bounds__(256) void gemm_mfma(const TA* __restrict__ A, int lda,
                                                 const float* __restrict__ W,
                                                 const float* __restrict__ bias,
                                                 TC* __restrict__ C, int ldc,
                                                 int Kfull,
                                                 const float* __restrict__ rms,
                                                 const float* __restrict__ nw,
                                                 size_t c_split) {
    constexpr int BK = 32;
    constexpr int MI = (BN == 128) ? 4 : (BM == 128 ? 2 : 1);
    constexpr int NI = 4;
    __shared__ bf16 As[BM * LDK];
    __shared__ bf16 Bs[BN * LDK];

    const int t = threadIdx.x;
    const int w = t >> 6, l = t & 63;
    const int bm = blockIdx.x * BM;
    const int bn = blockIdx.y * BN;
    const int wm = (BN == 128) ? (w >> 1) * 64 : w * (BM / 4);
    const int wn = (BN == 128) ? (w & 1) * 64 : 0;
    const int Kloop = Kfull / SPLITK;
    const int kb = (SPLITK > 1) ? blockIdx.z * Kloop : 0;
    if (SPLITK > 1) C += (size_t)blockIdx.z * c_split;

    f32x4 acc[MI][NI] = {};

    constexpr int EA = BM * BK / 256;
    constexpr int EB = BN * BK / 256;

    for (int k0 = 0; k0 < Kloop; k0 += BK) {
        const int kcur = kb + k0;
        __syncthreads();
        // ---- stage A tile (BM x 32) as bf16 ----
#pragma unroll
        for (int c = 0; c < EA / 8; ++c) {
            int flat = t * EA + c * 8;
            int row = flat >> 5;
            int kk = flat & 31;
            bf16 tmp[8];
            if constexpr (sizeof(TA) == 4) {
                const float4* src = (const float4*)(A + (size_t)(bm + row) * lda + kcur + kk);
                float4 v0 = src[0], v1 = src[1];
                float vals[8] = {v0.x, v0.y, v0.z, v0.w, v1.x, v1.y, v1.z, v1.w};
                float s = FRMS ? rms[bm + row] : 1.f;
#pragma unroll
                for (int j = 0; j < 8; ++j) {
                    float v = vals[j];
                    if (FRMS) v *= s * nw[kcur + kk + j];
                    tmp[j] = __float2bfloat16(v);
                }
            } else {
                *(uint4*)tmp = *(const uint4*)(A + (size_t)(bm + row) * lda + kcur + kk);
            }
            *(uint4*)(&As[row * LDK + kk]) = *(uint4*)tmp;
        }
        // ---- stage B tile (BN x 32) from f32 W ----
#pragma unroll
        for (int c = 0; c < EB / 8; ++c) {
            int flat = t * EB + c * 8;
            int row = flat >> 5;
            int kk = flat & 31;
            const float4* src = (const float4*)(W + (size_t)(bn + row) * Kfull + kcur + kk);
            float4 v0 = src[0], v1 = src[1];
            float vals[8] = {v0.x, v0.y, v0.z, v0.w, v1.x, v1.y, v1.z, v1.w};
            bf16 tmp[8];
#pragma unroll
            for (int j = 0; j < 8; ++j) tmp[j] = __float2bfloat16(vals[j]);
            *(uint4*)(&Bs[row * LDK + kk]) = *(uint4*)tmp;
        }
        __syncthreads();
        // ---- MFMA over the K=32 step ----
        bf16x8 af[MI], bfr[NI];
#pragma unroll
        for (int mi = 0; mi < MI; ++mi)
            af[mi] = *(const bf16x8*)(&As[(wm + mi * 16 + (l & 15)) * LDK + (l >> 4) * 8]);
#pragma unroll
        for (int ni = 0; ni < NI; ++ni)
            bfr[ni] = *(const bf16x8*)(&Bs[(wn + ni * 16 + (l & 15)) * LDK + (l >> 4) * 8]);
#pragma unroll
        for (int mi = 0; mi < MI; ++mi)
#pragma unroll
            for (int ni = 0; ni < NI; ++ni)
                acc[mi][ni] = __builtin_amdgcn_mfma_f32_16x16x32_bf16(af[mi], bfr[ni], acc[mi][ni], 0, 0, 0);
    }

    // ---- epilogue: C/D layout col=lane&15, row=(lane>>4)*4+r ----
#pragma unroll
    for (int mi = 0; mi < MI; ++mi) {
#pragma unroll
        for (int ni = 0; ni < NI; ++ni) {
            int col = bn + wn + ni * 16 + (l & 15);
            int rowb = bm + wm + mi * 16 + ((l >> 4) << 2);
            float bv = HASBIAS ? bias[col] : 0.f;
#pragma unroll
            for (int r = 0; r < 4; ++r) {
                float v = acc[mi][ni][r] + bv;
                if (ACT == 1) v = (v > 20.f) ? v : log1pf(__expf(v));
                size_t off = (size_t)(rowb + r) * ldc + col;
                if (ADDC) v += ldf(C, off);
                stf(C, off, v);
            }
        }
    }
}

// ---------------- depthwise causal conv (k=4) + SiLU; IN-PLACE on x-half of xz ----------------
__global__ void conv_silu_kernel(bf16* __restrict__ xz,
                                 const float* __restrict__ cw,
                                 const float* __restrict__ cb) {
    int gid = blockIdx.x * blockDim.x + threadIdx.x;
    int b = gid >> 10, d = gid & (DINNER - 1);
    float w0 = cw[d * 4 + 0], w1 = cw[d * 4 + 1], w2 = cw[d * 4 + 2], w3 = cw[d * 4 + 3];
    float bias = cb[d];
    bf16* col = xz + (size_t)b * SEQL * (2 * DINNER) + d;
    float x0 = 0.f, x1 = 0.f, x2 = 0.f;
#pragma unroll
    for (int t = 0; t < SEQL; ++t) {
        float x3 = __bfloat162float(col[(size_t)t * (2 * DINNER)]);
        float v = fmaf(w0, x0, fmaf(w1, x1, fmaf(w2, x2, fmaf(w3, x3, bias))));
        float s = 1.f / (1.f + __expf(-v));
        col[(size_t)t * (2 * DINNER)] = __float2bfloat16(v * s);
        x0 = x1; x1 = x2; x2 = x3;
    }
}

// ---------------- fused dt-proj + softplus + selective scan + gate ----------------
// thread per (b,d). xz: x-half holds xc (read) then y (written in-place); z-half read.
// xdb0/xdb1: split-K halves of xc @ x_proj^T, summed here. dt computed from LDS dt-cols.
__global__ void scan_kernel(bf16* __restrict__ xz,
                            const float* __restrict__ xdb0,
                            const float* __restrict__ xdb1,
                            const float* __restrict__ dtw,
                            const float* __restrict__ dtb,
                            const float* __restrict__ A_log,
                            const float* __restrict__ Dp) {
    int gid = blockIdx.x * blockDim.x + threadIdx.x;
    int b = gid >> 10, d = gid & (DINNER - 1);
    __shared__ float BCD[SEQL][XDBW];
    for (int idx = threadIdx.x; idx < SEQL * XDBW; idx += blockDim.x) {
        int t = idx >> 6, j = idx & 63;
        size_t o = ((size_t)b * SEQL + t) * XDBW + j;
        BCD[t][j] = xdb0[o] + xdb1[o];
    }
    __syncthreads();
    float w[DTRANK];
#pragma unroll
    for (int j = 0; j < DTRANK; ++j) w[j] = dtw[d * DTRANK + j];
    float bias = dtb[d];
    float Ac[DSTATE];
#pragma unroll
    for (int s = 0; s < DSTATE; ++s) Ac[s] = -__expf(A_log[d * DSTATE + s]);
    float Dd = Dp[d];
    float st[DSTATE];
#pragma unroll
    for (int s = 0; s < DSTATE; ++s) st[s] = 0.f;
    for (int t = 0; t < SEQL; ++t) {
        size_t roff = ((size_t)b * SEQL + t) * (2 * DINNER);
        // dt = softplus(dot(xdb_dt[t], w) + bias)
        float dtt = bias;
#pragma unroll
        for (int j = 0; j < DTRANK; ++j) dtt = fmaf(BCD[t][j], w[j], dtt);
        dtt = (dtt > 20.f) ? dtt : log1pf(__expf(dtt));
        float xt = __bfloat162float(xz[roff + d]);
        float zt = __bfloat162float(xz[roff + DINNER + d]);
        float dtx = dtt * xt;
        float yt = 0.f;
#pragma unroll
        for (int s = 0; s < DSTATE; ++s) {
            float dA = __expf(dtt * Ac[s]);
            st[s] = fmaf(st[s], dA, dtx * BCD[t][32 + s]);
            yt = fmaf(st[s], BCD[t][48 + s], yt);
        }
        float sz = zt / (1.f + __expf(-zt));
        xz[roff + d] = __float2bfloat16((yt + Dd * xt) * sz);
    }
}

// ---------------- final RMSNorm(last token) + classifier ----------------
__global__ void head_kernel(const float* __restrict__ h,
                            const float* __restrict__ fw,
                            const float* __restrict__ clsw,
                            const float* __restrict__ clsb,
                            float* __restrict__ out) {
    int b = blockIdx.x;
    int lane = threadIdx.x;
    const float* row = h + ((size_t)b * SEQL + (SEQL - 1)) * DIMM;
    const float4* p = (const float4*)row;
    float4 v0 = p[lane * 2], v1 = p[lane * 2 + 1];
    float ss = v0.x * v0.x + v0.y * v0.y + v0.z * v0.z + v0.w * v0.w +
               v1.x * v1.x + v1.y * v1.y + v1.z * v1.z + v1.w * v1.w;
#pragma unroll
    for (int off = 32; off > 0; off >>= 1) ss += __shfl_down(ss, off);
    ss = __shfl(ss, 0);
    float inv = rsqrtf(ss * (1.f / DIMM) + EPSV);
    const float4* wp = (const float4*)fw;
    float4 w0 = wp[lane * 2], w1 = wp[lane * 2 + 1];
    float nv[8];
    nv[0] = v0.x * inv * w0.x; nv[1] = v0.y * inv * w0.y;
    nv[2] = v0.z * inv * w0.z; nv[3] = v0.w * inv * w0.w;
    nv[4] = v1.x * inv * w1.x; nv[5] = v1.y * inv * w1.y;
    nv[6] = v1.z * inv * w1.z; nv[7] = v1.w * inv * w1.w;
    for (int c = 0; c < 10; ++c) {
        const float* cr = clsw + (size_t)c * DIMM + lane * 8;
        float pacc = 0.f;
#pragma unroll
        for (int j = 0; j < 8; ++j) pacc = fmaf(nv[j], cr[j], pacc);
#pragma unroll
        for (int off = 32; off > 0; off >>= 1) pacc += __shfl_down(pacc, off);
        if (lane == 0) out[b * 10 + c] = pacc + clsb[c];
    }
}

extern "C" void kernel_launch(void* const* d_in, const int* in_sizes, int n_in,
                              void* d_out, int out_size, void* d_ws, size_t ws_size,
                              hipStream_t stream) {
    const float* x     = (const float*)d_in[0];
    const float* rpw   = (const float*)d_in[1];
    const float* rpb   = (const float*)d_in[2];
    const float* normw = (const float*)d_in[3];
    const float* inpw  = (const float*)d_in[4];
    const float* inpb  = (const float*)d_in[5];
    const float* convw = (const float*)d_in[6];
    const float* convb = (const float*)d_in[7];
    const float* xpw   = (const float*)d_in[8];
    const float* dtpw  = (const float*)d_in[9];
    const float* dtpb  = (const float*)d_in[10];
    const float* alog  = (const float*)d_in[11];
    const float* Dp    = (const float*)d_in[12];
    const float* outpw = (const float*)d_in[13];
    const float* outpb = (const float*)d_in[14];
    const float* fnw   = (const float*)d_in[15];
    const float* clsw  = (const float*)d_in[16];
    const float* clsb  = (const float*)d_in[17];
    float* out = (float*)d_out;

    // per-row bytes: h(f32,512) + rms(f32) + xz(bf16,2048) + 2x xdb(f32,64)
    const size_t per_row = 512 * 4 + 4 + 2048 * 2 + 2 * 64 * 4;  // 6660 B
    const int cand[5] = {512, 256, 128, 64, 32};
    int Bc = 32;
    for (int i = 0; i < 5; ++i) {
        size_t R = (size_t)cand[i] * SEQL;
        if (R * per_row + 4096 <= ws_size) { Bc = cand[i]; break; }
    }
    const int chunks = BATCHN / Bc;
    const int R = Bc * SEQL;

    char* base = (char*)d_ws;
    float* h   = (float*)base; base += (size_t)R * DIMM * 4;
    float* rms = (float*)base; base += (size_t)R * 4;
    bf16* xz   = (bf16*)base;  base += (size_t)R * 2 * DINNER * 2;
    float* xdb = (float*)base; base += (size_t)R * XDBW * 4 * 2;  // two split-K halves

    for (int c = 0; c < chunks; ++c) {
        const int b0 = c * Bc;
        row_proj_kernel<<<dim3(R, DIMM / 256), 256, 0, stream>>>(
            x + (size_t)b0 * 784, rpw, rpb, h);

        for (int l = 0; l < 4; ++l) {
            rms_calc_kernel<<<R / 4, dim3(64, 4), 0, stream>>>(h, rms);

            // xz = rmsnorm(h) @ in_proj_w^T + b    (R x 2048, K=512)
            gemm_mfma<float, bf16, 128, 128, 0, false, true, true, 1>
                <<<dim3(R / 128, (2 * DINNER) / 128), 256, 0, stream>>>(
                h, DIMM, inpw + (size_t)l * 2 * DINNER * DIMM, inpb + (size_t)l * 2 * DINNER,
                xz, 2 * DINNER, DIMM, rms, normw + (size_t)l * DIMM, 0);

            // conv+silu in-place on x-half
            conv_silu_kernel<<<(Bc * DINNER) / 256, 256, 0, stream>>>(
                xz, convw + (size_t)l * DINNER * 4, convb + (size_t)l * DINNER);

            // xdb = xc @ x_proj_w^T    (R x 64, K=1024, split-K=2)
            gemm_mfma<bf16, float, 64, 64, 0, false, false, false, 2>
                <<<dim3(R / 64, 1, 2), 256, 0, stream>>>(
                xz, 2 * DINNER, xpw + (size_t)l * XDBW * DINNER, nullptr,
                xdb, XDBW, DINNER, nullptr, nullptr, (size_t)R * XDBW);

            // fused dt-proj + softplus + scan + gate; y overwrites xc in x-half
            scan_kernel<<<(Bc * DINNER) / 256, 256, 0, stream>>>(
                xz, xdb, xdb + (size_t)R * XDBW,
                dtpw + (size_t)l * DINNER * DTRANK, dtpb + (size_t)l * DINNER,
                alog + (size_t)l * DINNER * DSTATE, Dp + (size_t)l * DINNER);

            // h += y @ out_proj_w^T + b   (R x 512, K=1024)
            gemm_mfma<bf16, float, 128, 128, 0, true, true, false, 1>
                <<<dim3(R / 128, DIMM / 128), 256, 0, stream>>>(
                xz, 2 * DINNER, outpw + (size_t)l * DIMM * DINNER, outpb + (size_t)l * DIMM,
                h, DIMM, DINNER, nullptr, nullptr, 0);
        }
        head_kernel<<<Bc, 64, 0, stream>>>(h, fnw, clsw, clsb, out + (size_t)b0 * 10);
    }
}